// Round 1
// baseline (265.358 us; speedup 1.0000x reference)
//
#include <hip/hip_runtime.h>

// DerivativeNet direction='x': row-wise stencil + mask cumsum edges.
// B=16, C=2, H=1024, W=1024, fp32. Memory-bound: 320 MiB min traffic.

#define WDIM 1024

__global__ __launch_bounds__(256) void deriv_x_kernel(
    const float* __restrict__ u,
    const float* __restrict__ mask,
    float* __restrict__ out)
{
    const int row = blockIdx.x;          // b*1024 + y
    const int tid = threadIdx.x;         // 0..255, each owns 4 consecutive w
    const int b   = row >> 10;
    const int y   = row & 1023;

    __shared__ float sm [WDIM];
    __shared__ float su0[WDIM];
    __shared__ float su1[WDIM];
    __shared__ int   wsum[4];

    // ---- global loads (float4, fully coalesced) ----
    const size_t mrow_off = (size_t)row * WDIM;                       // mask[b,0,y,:]
    const size_t u0_off   = ((size_t)(b * 2 + 0) * WDIM + y) * WDIM;  // u[b,0,y,:]
    const size_t u1_off   = ((size_t)(b * 2 + 1) * WDIM + y) * WDIM;  // u[b,1,y,:]

    const float4 m4 = ((const float4*)(mask + mrow_off))[tid];
    const float4 a4 = ((const float4*)(u + u0_off))[tid];
    const float4 c4 = ((const float4*)(u + u1_off))[tid];

    ((float4*)sm )[tid] = m4;
    ((float4*)su0)[tid] = a4;
    ((float4*)su1)[tid] = c4;

    // ---- per-row mask scan (integers: exact vs reference float cumsum) ----
    const int m0 = (int)m4.x, m1 = (int)m4.y, m2 = (int)m4.z, m3 = (int)m4.w;
    const int cnt = m0 + m1 + m2 + m3;
    int incl = cnt;
    #pragma unroll
    for (int off = 1; off < 64; off <<= 1) {
        int n = __shfl_up(incl, off, 64);
        if ((tid & 63) >= off) incl += n;
    }
    const int wave = tid >> 6;
    if ((tid & 63) == 63) wsum[wave] = incl;

    __syncthreads();   // single barrier: covers sm/su0/su1/wsum

    const int s0 = wsum[0], s1 = wsum[1], s2 = wsum[2], s3 = wsum[3];
    const int total = s0 + s1 + s2 + s3;
    int wave_off = 0;
    if (wave > 0) wave_off += s0;
    if (wave > 1) wave_off += s1;
    if (wave > 2) wave_off += s2;
    const int excl = wave_off + incl - cnt;

    // cumsum at each of the 4 owned elements
    const int cs0 = excl + m0;
    const int cs1 = cs0 + m1;
    const int cs2 = cs1 + m2;
    const int cs3 = cs2 + m3;

    const int base = tid * 4;
    const int mlft = (tid > 0)   ? (int)sm[base - 1] : 0;   // zero-pad
    const int mrgt = (tid < 255) ? (int)sm[base + 4] : 0;

    // eroded: 3-box == 3
    const float er0 = (mlft + m0 + m1 == 3) ? 1.f : 0.f;
    const float er1 = (m0 + m1 + m2   == 3) ? 1.f : 0.f;
    const float er2 = (m1 + m2 + m3   == 3) ? 1.f : 0.f;
    const float er3 = (m2 + m3 + mrgt == 3) ? 1.f : 0.f;

    // edge1: cs == 1 ; edge2: cs == rowtotal && mask
    const float e10 = (cs0 == 1) ? 1.f : 0.f;
    const float e11 = (cs1 == 1) ? 1.f : 0.f;
    const float e12 = (cs2 == 1) ? 1.f : 0.f;
    const float e13 = (cs3 == 1) ? 1.f : 0.f;
    const float e20 = (m0 && cs0 == total) ? 1.f : 0.f;
    const float e21 = (m1 && cs1 == total) ? 1.f : 0.f;
    const float e22 = (m2 && cs2 == total) ? 1.f : 0.f;
    const float e23 = (m3 && cs3 == total) ? 1.f : 0.f;

    const float inv2h = 1.0f / (2.0f * 0.01f);   // 50
    const float invh  = 1.0f / 0.01f;            // 100

#define DO_CH(SU, V, OFF)                                                          \
    {                                                                              \
        const float ul = (tid > 0)   ? SU[base - 1] : 0.f;                         \
        const float ur = (tid < 255) ? SU[base + 4] : 0.f;                         \
        const float l0 = ul,    r0 = V.y;                                          \
        const float l1 = V.x,   r1 = V.z;                                          \
        const float l2 = V.y,   r2 = V.w;                                          \
        const float l3 = V.z,   r3 = ur;                                           \
        float4 o;                                                                  \
        o.x = er0*((r0-l0)*inv2h) + e10*((r0-V.x)*invh) + e20*((V.x-l0)*invh);     \
        o.y = er1*((r1-l1)*inv2h) + e11*((r1-V.y)*invh) + e21*((V.y-l1)*invh);     \
        o.z = er2*((r2-l2)*inv2h) + e12*((r2-V.z)*invh) + e22*((V.z-l2)*invh);     \
        o.w = er3*((r3-l3)*inv2h) + e13*((r3-V.w)*invh) + e23*((V.w-l3)*invh);     \
        ((float4*)(out + OFF))[tid] = o;                                           \
    }

    DO_CH(su0, a4, u0_off)
    DO_CH(su1, c4, u1_off)
#undef DO_CH
}

extern "C" void kernel_launch(void* const* d_in, const int* in_sizes, int n_in,
                              void* d_out, int out_size, void* d_ws, size_t ws_size,
                              hipStream_t stream) {
    const float* u    = (const float*)d_in[0];
    const float* mask = (const float*)d_in[1];
    float* out        = (float*)d_out;
    // grid: one block per (b, y) row = 16*1024
    deriv_x_kernel<<<dim3(16 * 1024), dim3(256), 0, stream>>>(u, mask, out);
}